// Round 2
// baseline (464.743 us; speedup 1.0000x reference)
//
#include <hip/hip_runtime.h>
#include <cmath>

#define SEQ 2048
#define BATCH 2

typedef float v4f __attribute__((ext_vector_type(4)));

// ---------------- Kernel 1: q,k = normalize(mv_linear(x, W)) ----------------
// One block per output position n. 256 threads strided over m (the 2048-dot).
// W layout (n, m, g) -> row W[n,:,:] is 32 KB contiguous, read as float4.
// acc layout: v = t_sel*16 + b*8 + i   (t_sel: 0=q, 1=k)
__global__ __launch_bounds__(256) void qk_kernel(
    const float* __restrict__ x,    // (2, 2048, 8)
    const float* __restrict__ Wq,   // (2048, 2048, 4)
    const float* __restrict__ Wk,   // (2048, 2048, 4)
    const float* __restrict__ a,    // (3000, 4)
    float* __restrict__ qout,       // (2, 2048, 8)
    float* __restrict__ kout)       // (2, 2048, 8)
{
    const int n   = blockIdx.x;
    const int tid = threadIdx.x;

    float acc[32];
#pragma unroll
    for (int v = 0; v < 32; v++) acc[v] = 0.f;

    const v4f* wq4 = (const v4f*)(Wq + (size_t)n * SEQ * 4);
    const v4f* wk4 = (const v4f*)(Wk + (size_t)n * SEQ * 4);
    const v4f* x4  = (const v4f*)x;

    for (int m = tid; m < SEQ; m += 256) {
        v4f wq = wq4[m];
        v4f wk = wk4[m];
        const float wqg[4] = {wq.x, wq.y, wq.z, wq.w};
        const float wkg[4] = {wk.x, wk.y, wk.z, wk.w};
#pragma unroll
        for (int b = 0; b < BATCH; b++) {
            v4f xa = x4[((size_t)b * SEQ + m) * 2];
            v4f xb = x4[((size_t)b * SEQ + m) * 2 + 1];
            const float xv[8] = {xa.x, xa.y, xa.z, xa.w, xb.x, xb.y, xb.z, xb.w};
            const int g[8] = {0, 1, 1, 1, 2, 2, 2, 3};
#pragma unroll
            for (int i = 0; i < 8; i++) {
                acc[0 * 16 + b * 8 + i] += wqg[g[i]] * xv[i];
                acc[1 * 16 + b * 8 + i] += wkg[g[i]] * xv[i];
            }
        }
    }

    // wave-64 butterfly reduce each of the 32 partials
#pragma unroll
    for (int v = 0; v < 32; v++) {
#pragma unroll
        for (int off = 32; off >= 1; off >>= 1)
            acc[v] += __shfl_down(acc[v], off, 64);
    }

    __shared__ float red[4][32];
    __shared__ float fin[32];
    const int wave = tid >> 6;
    const int lane = tid & 63;
    if (lane == 0) {
#pragma unroll
        for (int v = 0; v < 32; v++) red[wave][v] = acc[v];
    }
    __syncthreads();
    if (tid < 32) fin[tid] = red[0][tid] + red[1][tid] + red[2][tid] + red[3][tid];
    __syncthreads();

    // 4 threads: (t_sel, b) each -> normalization epilogue + write 8 floats
    if (tid < 4) {
        const int t_sel = tid >> 1;
        const int b     = tid & 1;
        float v[8];
#pragma unroll
        for (int i = 0; i < 8; i++) v[i] = fin[t_sel * 16 + b * 8 + i];

        float nr[4];
        nr[0] = fabsf(v[0]);
        nr[1] = sqrtf(v[1] * v[1] + v[2] * v[2] + v[3] * v[3]);
        nr[2] = sqrtf(v[4] * v[4] + v[5] * v[5] + v[6] * v[6]);
        nr[3] = fabsf(v[7]);

        float sc[4];
#pragma unroll
        for (int gg = 0; gg < 4; gg++) {
            float sg = 1.f / (1.f + __expf(-a[n * 4 + gg]));   // sigmoid
            sc[gg]   = 1.f / (sg * (nr[gg] - 1.f) + 1.f + 1e-6f);
        }

        float* dst = (t_sel ? kout : qout) + ((size_t)b * SEQ + n) * 8;
        const int g[8] = {0, 1, 1, 1, 2, 2, 2, 3};
#pragma unroll
        for (int i = 0; i < 8; i++) dst[i] = v[i] * sc[g[i]];
    }
}

// ---------------- Kernel 2: pairwise geometric product ----------------
// Block = one (b, s); 256 threads x 8 iters cover t in [0,2048).
// Each thread loads k[b,t,:] (32 B, coalesced) and streams out[b,s,t,:] (32 B).
__global__ __launch_bounds__(256) void gp_kernel(
    const float* __restrict__ q,
    const float* __restrict__ k,
    float* __restrict__ out)
{
    const int bs  = blockIdx.x;
    const int b   = bs >> 11;           // / 2048
    const int s   = bs & (SEQ - 1);
    const int tid = threadIdx.x;

    __shared__ float qs[8];
    if (tid < 8) qs[tid] = q[((size_t)b * SEQ + s) * 8 + tid];
    __syncthreads();
    const float q0 = qs[0], q1 = qs[1], q2 = qs[2], q3 = qs[3],
                q4 = qs[4], q5 = qs[5], q6 = qs[6], q7 = qs[7];

    const v4f* kp  = (const v4f*)(k + (size_t)b * SEQ * 8);
    v4f* out4 = (v4f*)(out + ((size_t)b * SEQ + s) * (size_t)SEQ * 8);

#pragma unroll
    for (int j = 0; j < 8; j++) {
        const int t = tid + j * 256;
        v4f ka = kp[t * 2];
        v4f kb = kp[t * 2 + 1];
        const float k0 = ka.x, k1 = ka.y, k2 = ka.z, k3 = ka.w;
        const float k4 = kb.x, k5 = kb.y, k6 = kb.z, k7 = kb.w;

        // Cl(3,0) geometric product, blade order [1,e1,e2,e3,e12,e13,e23,e123]
        v4f oa, ob;
        oa.x = q0*k0 + q1*k1 + q2*k2 + q3*k3 - q4*k4 - q5*k5 - q6*k6 - q7*k7;
        oa.y = q0*k1 + q1*k0 - q2*k4 - q3*k5 + q4*k2 + q5*k3 - q6*k7 - q7*k6;
        oa.z = q0*k2 + q1*k4 + q2*k0 - q3*k6 - q4*k1 + q5*k7 + q6*k3 + q7*k5;
        oa.w = q0*k3 + q1*k5 + q2*k6 + q3*k0 - q4*k7 - q5*k1 - q6*k2 - q7*k4;
        ob.x = q0*k4 + q1*k2 - q2*k1 + q3*k7 + q4*k0 - q5*k6 + q6*k5 + q7*k3;
        ob.y = q0*k5 + q1*k3 - q2*k7 - q3*k1 + q4*k6 + q5*k0 - q6*k4 - q7*k2;
        ob.z = q0*k6 + q1*k7 + q2*k3 - q3*k2 - q4*k5 + q5*k4 + q6*k0 + q7*k1;
        ob.w = q0*k7 + q1*k6 - q2*k5 + q3*k4 + q4*k3 - q5*k2 + q6*k1 + q7*k0;

        __builtin_nontemporal_store(oa, &out4[t * 2]);
        __builtin_nontemporal_store(ob, &out4[t * 2 + 1]);
    }
}

extern "C" void kernel_launch(void* const* d_in, const int* in_sizes, int n_in,
                              void* d_out, int out_size, void* d_ws, size_t ws_size,
                              hipStream_t stream) {
    const float* x  = (const float*)d_in[0];   // (2, 2048, 8)
    const float* Wq = (const float*)d_in[1];   // (2048, 2048, 4)
    const float* Wk = (const float*)d_in[2];   // (2048, 2048, 4)
    const float* a  = (const float*)d_in[3];   // (3000, 4)
    float* out = (float*)d_out;                // (2, 2048, 2048, 8)

    float* q = (float*)d_ws;                        // (2, 2048, 8) = 128 KB
    float* k = q + (size_t)BATCH * SEQ * 8;         // (2, 2048, 8) = 128 KB

    qk_kernel<<<SEQ, 256, 0, stream>>>(x, Wq, Wk, a, q, k);
    gp_kernel<<<BATCH * SEQ, 256, 0, stream>>>(q, k, out);
}

// Round 3
// 376.751 us; speedup vs baseline: 1.2336x; 1.2336x over previous
//
#include <hip/hip_runtime.h>
#include <cmath>

#define SEQ 2048
#define BATCH 2

typedef float v4f __attribute__((ext_vector_type(4)));

// ---------------- Kernel 1: q,k = normalize(mv_linear(x, W)) ----------------
// One block per output position n. Waves 0-1 compute q, waves 2-3 compute k
// (t_sel = tid>>7). Each half strides m by 128 over the 2048-long dot.
// Reduction: conflict-free LDS transpose (stride 129) + width-8 shuffle.
__global__ __launch_bounds__(256) void qk_kernel(
    const float* __restrict__ x,    // (2, 2048, 8)
    const float* __restrict__ Wq,   // (2048, 2048, 4)
    const float* __restrict__ Wk,   // (2048, 2048, 4)
    const float* __restrict__ a,    // (3000, 4)
    float* __restrict__ qout,       // (2, 2048, 8)
    float* __restrict__ kout)       // (2, 2048, 8)
{
    const int n     = blockIdx.x;
    const int tid   = threadIdx.x;
    const int t_sel = tid >> 7;      // 0 = q, 1 = k
    const int tl    = tid & 127;

    const float* W  = t_sel ? Wk : Wq;
    const v4f* w4   = (const v4f*)(W + (size_t)n * SEQ * 4);
    const v4f* x4   = (const v4f*)x;

    float acc[16];
#pragma unroll
    for (int v = 0; v < 16; v++) acc[v] = 0.f;

    for (int m = tl; m < SEQ; m += 128) {
        v4f w = w4[m];
        const float wg[4] = {w.x, w.y, w.z, w.w};
#pragma unroll
        for (int b = 0; b < BATCH; b++) {
            v4f xa = x4[((size_t)b * SEQ + m) * 2];
            v4f xb = x4[((size_t)b * SEQ + m) * 2 + 1];
            const float xv[8] = {xa.x, xa.y, xa.z, xa.w, xb.x, xb.y, xb.z, xb.w};
            const int g[8] = {0, 1, 1, 1, 2, 2, 2, 3};
#pragma unroll
            for (int i = 0; i < 8; i++)
                acc[b * 8 + i] += wg[g[i]] * xv[i];
        }
    }

    // LDS reduce: 32 outputs x 128 partials, stride 129 (conflict-free)
    __shared__ float lds[32 * 129];
    __shared__ float fin[32];
#pragma unroll
    for (int v = 0; v < 16; v++)
        lds[(t_sel * 16 + v) * 129 + tl] = acc[v];
    __syncthreads();

    {
        const int v    = tid >> 3;   // 0..31 output index
        const int sgrp = tid & 7;    // 8 threads per output
        const float* row = &lds[v * 129 + sgrp * 16];
        float p = 0.f;
#pragma unroll
        for (int i = 0; i < 16; i++) p += row[i];
        p += __shfl_down(p, 4, 8);
        p += __shfl_down(p, 2, 8);
        p += __shfl_down(p, 1, 8);
        if (sgrp == 0) fin[v] = p;
    }
    __syncthreads();

    // 4 threads: (t_sel, b) each -> normalization epilogue + write 8 floats
    if (tid < 4) {
        const int ts = tid >> 1;
        const int b  = tid & 1;
        float v[8];
#pragma unroll
        for (int i = 0; i < 8; i++) v[i] = fin[ts * 16 + b * 8 + i];

        float nr[4];
        nr[0] = fabsf(v[0]);
        nr[1] = sqrtf(v[1] * v[1] + v[2] * v[2] + v[3] * v[3]);
        nr[2] = sqrtf(v[4] * v[4] + v[5] * v[5] + v[6] * v[6]);
        nr[3] = fabsf(v[7]);

        float sc[4];
#pragma unroll
        for (int gg = 0; gg < 4; gg++) {
            float sg = 1.f / (1.f + __expf(-a[n * 4 + gg]));   // sigmoid
            sc[gg]   = 1.f / (sg * (nr[gg] - 1.f) + 1.f + 1e-6f);
        }

        float* dst = (ts ? kout : qout) + ((size_t)b * SEQ + n) * 8;
        const int g[8] = {0, 1, 1, 1, 2, 2, 2, 3};
#pragma unroll
        for (int i = 0; i < 8; i++) dst[i] = v[i] * sc[g[i]];
    }
}

// ---------------- Kernel 2: pairwise geometric product ----------------
// Block = one (b, s). Linear float4 index f = tid + j*256 over the 4096
// float4s of out[b,s,:,:] -> every 64-lane NT store is a dense 1 KB line.
// Lane pair (2r, 2r+1) shares t = f>>1; each lane computes the full product
// and selects its half (predicated, no branch).
__global__ __launch_bounds__(256) void gp_kernel(
    const float* __restrict__ q,
    const float* __restrict__ k,
    float* __restrict__ out)
{
    const int bs  = blockIdx.x;
    const int b   = bs >> 11;           // / 2048
    const int s   = bs & (SEQ - 1);
    const int tid = threadIdx.x;

    __shared__ float qs[8];
    if (tid < 8) qs[tid] = q[((size_t)b * SEQ + s) * 8 + tid];
    __syncthreads();
    const float q0 = qs[0], q1 = qs[1], q2 = qs[2], q3 = qs[3],
                q4 = qs[4], q5 = qs[5], q6 = qs[6], q7 = qs[7];

    const v4f* kp = (const v4f*)(k + (size_t)b * SEQ * 8);
    v4f* out4 = (v4f*)(out + ((size_t)b * SEQ + s) * (size_t)SEQ * 8);

    const bool hi = (tid & 1);

#pragma unroll 4
    for (int j = 0; j < 16; j++) {
        const int f = tid + j * 256;    // 0..4095 linear float4 index
        const int t = f >> 1;
        v4f ka = kp[t * 2];
        v4f kb = kp[t * 2 + 1];
        const float k0 = ka.x, k1 = ka.y, k2 = ka.z, k3 = ka.w;
        const float k4 = kb.x, k5 = kb.y, k6 = kb.z, k7 = kb.w;

        // Cl(3,0) geometric product, blade order [1,e1,e2,e3,e12,e13,e23,e123]
        v4f oa, ob;
        oa.x = q0*k0 + q1*k1 + q2*k2 + q3*k3 - q4*k4 - q5*k5 - q6*k6 - q7*k7;
        oa.y = q0*k1 + q1*k0 - q2*k4 - q3*k5 + q4*k2 + q5*k3 - q6*k7 - q7*k6;
        oa.z = q0*k2 + q1*k4 + q2*k0 - q3*k6 - q4*k1 + q5*k7 + q6*k3 + q7*k5;
        oa.w = q0*k3 + q1*k5 + q2*k6 + q3*k0 - q4*k7 - q5*k1 - q6*k2 - q7*k4;
        ob.x = q0*k4 + q1*k2 - q2*k1 + q3*k7 + q4*k0 - q5*k6 + q6*k5 + q7*k3;
        ob.y = q0*k5 + q1*k3 - q2*k7 - q3*k1 + q4*k6 + q5*k0 - q6*k4 - q7*k2;
        ob.z = q0*k6 + q1*k7 + q2*k3 - q3*k2 - q4*k5 + q5*k4 + q6*k0 + q7*k1;
        ob.w = q0*k7 + q1*k6 - q2*k5 + q3*k4 + q4*k3 - q5*k2 + q6*k1 + q7*k0;

        v4f o = hi ? ob : oa;
        __builtin_nontemporal_store(o, &out4[f]);
    }
}

extern "C" void kernel_launch(void* const* d_in, const int* in_sizes, int n_in,
                              void* d_out, int out_size, void* d_ws, size_t ws_size,
                              hipStream_t stream) {
    const float* x  = (const float*)d_in[0];   // (2, 2048, 8)
    const float* Wq = (const float*)d_in[1];   // (2048, 2048, 4)
    const float* Wk = (const float*)d_in[2];   // (2048, 2048, 4)
    const float* a  = (const float*)d_in[3];   // (3000, 4)
    float* out = (float*)d_out;                // (2, 2048, 2048, 8)

    float* q = (float*)d_ws;                        // (2, 2048, 8) = 128 KB
    float* k = q + (size_t)BATCH * SEQ * 8;         // (2, 2048, 8) = 128 KB

    qk_kernel<<<SEQ, 256, 0, stream>>>(x, Wq, Wk, a, q, k);
    gp_kernel<<<BATCH * SEQ, 256, 0, stream>>>(q, k, out);
}